// Round 1
// baseline (366.249 us; speedup 1.0000x reference)
//
#include <hip/hip_runtime.h>
#include <stdint.h>

#define CDIM 768
#define HDIM 48

typedef float  f32x4  __attribute__((ext_vector_type(4)));
typedef short  bf16x8 __attribute__((ext_vector_type(8)));
typedef unsigned short u16x4 __attribute__((ext_vector_type(4)));

__device__ __forceinline__ unsigned short f2bf(float x) {
    union { float f; uint32_t u; } v; v.f = x;
    return (unsigned short)((v.u + 0x7FFFu + ((v.u >> 16) & 1u)) >> 16);
}

// ---------------- prep: pack weights into MFMA fragment order ----------------
// w1p: (kt 0..23, nt 0..2) frags of W1' = diag(gamma)*W1   [16x16x32 B-layout]
// w2p: (kt 0..1,  ct 0..47) frags of W2 (K 48 padded to 64 with zeros)
// b1p[j] = b1[j] + sum_c beta[c]*W1[c][j];  cs1[j] = sum_c gamma[c]*W1[c][j]
__global__ __launch_bounds__(256) void prep_kernel(
    const float* __restrict__ W1, const float* __restrict__ b1,
    const float* __restrict__ W2,
    const float* __restrict__ gamma, const float* __restrict__ beta,
    unsigned short* __restrict__ w1p, unsigned short* __restrict__ w2p,
    float* __restrict__ b1p, float* __restrict__ cs1)
{
    const int blk = blockIdx.x, tid = threadIdx.x;
    const int l = tid & 63;
    if (blk < 18) {                       // 72 W1 frags, 4/block
        const int fid = blk * 4 + (tid >> 6);
        const int kt = fid / 3, nt = fid % 3;
        const int k0 = kt * 32 + 8 * (l >> 4);
        const int n  = nt * 16 + (l & 15);
        bf16x8 v;
        #pragma unroll
        for (int b = 0; b < 8; ++b) {
            const int k = k0 + b;
            v[b] = (short)f2bf(gamma[k] * W1[k * HDIM + n]);
        }
        *reinterpret_cast<bf16x8*>(w1p + (size_t)(fid * 64 + l) * 8) = v;
    } else if (blk < 42) {                // 96 W2 frags, 4/block
        const int fid = (blk - 18) * 4 + (tid >> 6);
        const int kt = fid / 48, nt = fid % 48;
        const int k0 = kt * 32 + 8 * (l >> 4);
        const int n  = nt * 16 + (l & 15);
        bf16x8 v;
        #pragma unroll
        for (int b = 0; b < 8; ++b) {
            const int k = k0 + b;
            const float w = (k < HDIM) ? W2[k * CDIM + n] : 0.0f;
            v[b] = (short)f2bf(w);
        }
        *reinterpret_cast<bf16x8*>(w2p + (size_t)(fid * 64 + l) * 8) = v;
    } else {                              // b1p / cs1 reductions
        const int j = tid >> 2, p = tid & 3;
        float sb = 0.f, sg = 0.f;
        if (j < HDIM) {
            for (int c = p * 192; c < (p + 1) * 192; ++c) {
                const float w = W1[c * HDIM + j];
                sb += beta[c]  * w;
                sg += gamma[c] * w;
            }
        }
        sb += __shfl_xor(sb, 1); sb += __shfl_xor(sb, 2);
        sg += __shfl_xor(sg, 1); sg += __shfl_xor(sg, 2);
        if (p == 0 && j < HDIM) { b1p[j] = b1[j] + sb; cs1[j] = sg; }
    }
}

// ---------------- main fused kernel: 1 wave = 16 rows ----------------
// GEMM1 on RAW x (LN folded in afterwards):
//   hid = rstd*(x@W1' - mu*cs1) + b1'   then QuickGELU, then GEMM2 + residual.
// MFMA called operand-swapped (A=weights, B=activations) so each lane's 4 acc
// regs are 4 consecutive output channels of ONE row -> float4 epilogue.
__global__ __launch_bounds__(256) void mlp_kernel(
    const float* __restrict__ x,
    const float* __restrict__ b2,
    const unsigned short* __restrict__ w1p,
    const unsigned short* __restrict__ w2p,
    const float* __restrict__ b1p,
    const float* __restrict__ cs1,
    float* __restrict__ out)
{
    __shared__ __align__(16) unsigned short lds_hid[4][16][72]; // stride 72 -> 2-way banks (free)
    const int tid  = threadIdx.x;
    const int w    = tid >> 6;
    const int l    = tid & 63;
    const int lrow = l & 15;    // outer index lane (row of x for B-frags)
    const int lg   = l >> 4;    // k-group
    const size_t m0 = ((size_t)blockIdx.x * 4 + w) * 16;

    const float* __restrict__ xrow = x + (m0 + lrow) * CDIM + 8 * lg;
    const bf16x8* __restrict__ w1f = reinterpret_cast<const bf16x8*>(w1p);
    const bf16x8* __restrict__ w2f = reinterpret_cast<const bf16x8*>(w2p);

    f32x4 acc1[3];
    #pragma unroll
    for (int nt = 0; nt < 3; ++nt) { acc1[nt][0]=0.f; acc1[nt][1]=0.f; acc1[nt][2]=0.f; acc1[nt][3]=0.f; }

    // GEMM1 + fused row stats (4 lanes l, l^16, l^32, l^48 cover row lrow)
    float rsum = 0.f, rsq = 0.f;
    for (int kt = 0; kt < 24; ++kt) {
        const f32x4 xa = *reinterpret_cast<const f32x4*>(xrow + kt * 32);
        const f32x4 xb = *reinterpret_cast<const f32x4*>(xrow + kt * 32 + 4);
        bf16x8 bf;
        #pragma unroll
        for (int b = 0; b < 4; ++b) {
            rsum += xa[b]; rsq += xa[b] * xa[b];
            rsum += xb[b]; rsq += xb[b] * xb[b];
            bf[b]     = (short)f2bf(xa[b]);
            bf[b + 4] = (short)f2bf(xb[b]);
        }
        acc1[0] = __builtin_amdgcn_mfma_f32_16x16x32_bf16(w1f[(kt*3+0)*64 + l], bf, acc1[0], 0, 0, 0);
        acc1[1] = __builtin_amdgcn_mfma_f32_16x16x32_bf16(w1f[(kt*3+1)*64 + l], bf, acc1[1], 0, 0, 0);
        acc1[2] = __builtin_amdgcn_mfma_f32_16x16x32_bf16(w1f[(kt*3+2)*64 + l], bf, acc1[2], 0, 0, 0);
    }
    rsum += __shfl_xor(rsum, 16); rsum += __shfl_xor(rsum, 32);
    rsq  += __shfl_xor(rsq , 16); rsq  += __shfl_xor(rsq , 32);
    const float mu   = rsum * (1.f / 768.f);
    const float var  = rsq * (1.f / 768.f) - mu * mu;
    const float rstd = rsqrtf(var + 1e-5f);

    // zero the k-pad region (cols 48..63) of this wave's hid tile
    *reinterpret_cast<unsigned long long*>(&lds_hid[w][l >> 2][48 + (l & 3) * 4]) = 0ull;

    // LN fixup + bias + QuickGELU -> LDS bf16 (lane owns 4 consecutive channels of row lrow)
    #pragma unroll
    for (int nt = 0; nt < 3; ++nt) {
        const int c4 = nt * 16 + 4 * lg;
        const f32x4 bb = *reinterpret_cast<const f32x4*>(b1p + c4);
        const f32x4 cs = *reinterpret_cast<const f32x4*>(cs1 + c4);
        u16x4 pk;
        #pragma unroll
        for (int r = 0; r < 4; ++r) {
            const float h = rstd * (acc1[nt][r] - mu * cs[r]) + bb[r];
            const float g = h / (1.f + __expf(-1.702f * h));
            pk[r] = f2bf(g);
        }
        *reinterpret_cast<u16x4*>(&lds_hid[w][lrow][c4]) = pk;
    }
    __syncthreads();   // also orders same-wave LDS write->read conservatively

    const bf16x8 a2_0 = *reinterpret_cast<const bf16x8*>(&lds_hid[w][lrow][8 * lg]);
    const bf16x8 a2_1 = *reinterpret_cast<const bf16x8*>(&lds_hid[w][lrow][8 * lg + 32]);

    const float* __restrict__ xres = x   + (m0 + lrow) * CDIM;
    float* __restrict__       ores = out + (m0 + lrow) * CDIM;

    // GEMM2 (48 ctiles in 6 chunks of 8) + fused residual epilogue
    #pragma unroll 1
    for (int ch = 0; ch < 6; ++ch) {
        f32x4 acc2[8];
        #pragma unroll
        for (int n8 = 0; n8 < 8; ++n8) { acc2[n8][0]=0.f; acc2[n8][1]=0.f; acc2[n8][2]=0.f; acc2[n8][3]=0.f; }
        #pragma unroll
        for (int n8 = 0; n8 < 8; ++n8) {
            const int ct = ch * 8 + n8;
            acc2[n8] = __builtin_amdgcn_mfma_f32_16x16x32_bf16(w2f[ct * 64 + l],        a2_0, acc2[n8], 0, 0, 0);
            acc2[n8] = __builtin_amdgcn_mfma_f32_16x16x32_bf16(w2f[(48 + ct) * 64 + l], a2_1, acc2[n8], 0, 0, 0);
        }
        #pragma unroll
        for (int n8 = 0; n8 < 8; ++n8) {
            const int c4 = (ch * 8 + n8) * 16 + 4 * lg;
            const f32x4 bb = *reinterpret_cast<const f32x4*>(b2 + c4);
            const f32x4 xr = *reinterpret_cast<const f32x4*>(xres + c4);
            f32x4 o;
            #pragma unroll
            for (int r = 0; r < 4; ++r) o[r] = acc2[n8][r] + bb[r] + xr[r];
            *reinterpret_cast<f32x4*>(ores + c4) = o;
        }
    }
}

extern "C" void kernel_launch(void* const* d_in, const int* in_sizes, int n_in,
                              void* d_out, int out_size, void* d_ws, size_t ws_size,
                              hipStream_t stream)
{
    const float* x     = (const float*)d_in[0];
    const float* W1    = (const float*)d_in[1];
    const float* b1    = (const float*)d_in[2];
    const float* W2    = (const float*)d_in[3];
    const float* b2    = (const float*)d_in[4];
    const float* gamma = (const float*)d_in[5];
    const float* beta  = (const float*)d_in[6];
    float* out = (float*)d_out;

    unsigned short* w1p = (unsigned short*)d_ws;     // 72 frags * 512 B  = 73728 B
    unsigned short* w2p = w1p + 24 * 3 * 64 * 8;     // 96 frags * 512 B  = 98304 B
    float* b1p = (float*)(w2p + 2 * 48 * 64 * 8);    // 48 f32
    float* cs1 = b1p + 64;                           // 48 f32 (16B-aligned gap)

    const int M = in_sizes[0] / CDIM;   // 131072 rows
    const int tiles = M / 16;           // 8192 (one per wave)

    prep_kernel<<<dim3(43), dim3(256), 0, stream>>>(W1, b1, W2, gamma, beta, w1p, w2p, b1p, cs1);
    mlp_kernel<<<dim3(tiles / 4), dim3(256), 0, stream>>>(x, b2, w1p, w2p, b1p, cs1, out);
}

// Round 2
// 304.827 us; speedup vs baseline: 1.2015x; 1.2015x over previous
//
#include <hip/hip_runtime.h>
#include <hip/hip_bf16.h>
#include <stdint.h>

#define CDIM 768
#define HDIM 48

typedef float  f32x4  __attribute__((ext_vector_type(4)));
typedef short  bf16x8 __attribute__((ext_vector_type(8)));
typedef unsigned short u16x4 __attribute__((ext_vector_type(4)));

__device__ __forceinline__ unsigned short f2bf(float x) {
    __hip_bfloat16 h = __float2bfloat16(x);   // HW RNE convert
    return *reinterpret_cast<unsigned short*>(&h);
}

// ---------------- prep: pack weights into MFMA fragment order ----------------
// w1p: (kt 0..23, nt 0..2) frags of W1' = diag(gamma)*W1   [16x16x32 B-layout]
// w2p: (kt 0..1,  ct 0..47) frags of W2 (K 48 padded to 64 with zeros)
// b1p[j] = b1[j] + sum_c beta[c]*W1[c][j];  cs1[j] = sum_c gamma[c]*W1[c][j]
__global__ __launch_bounds__(256) void prep_kernel(
    const float* __restrict__ W1, const float* __restrict__ b1,
    const float* __restrict__ W2,
    const float* __restrict__ gamma, const float* __restrict__ beta,
    unsigned short* __restrict__ w1p, unsigned short* __restrict__ w2p,
    float* __restrict__ b1p, float* __restrict__ cs1)
{
    const int blk = blockIdx.x, tid = threadIdx.x;
    const int l = tid & 63;
    if (blk < 18) {                       // 72 W1 frags, 4/block
        const int fid = blk * 4 + (tid >> 6);
        const int kt = fid / 3, nt = fid % 3;
        const int k0 = kt * 32 + 8 * (l >> 4);
        const int n  = nt * 16 + (l & 15);
        bf16x8 v;
        #pragma unroll
        for (int b = 0; b < 8; ++b) {
            const int k = k0 + b;
            v[b] = (short)f2bf(gamma[k] * W1[k * HDIM + n]);
        }
        *reinterpret_cast<bf16x8*>(w1p + (size_t)(fid * 64 + l) * 8) = v;
    } else if (blk < 42) {                // 96 W2 frags, 4/block
        const int fid = (blk - 18) * 4 + (tid >> 6);
        const int kt = fid / 48, nt = fid % 48;
        const int k0 = kt * 32 + 8 * (l >> 4);
        const int n  = nt * 16 + (l & 15);
        bf16x8 v;
        #pragma unroll
        for (int b = 0; b < 8; ++b) {
            const int k = k0 + b;
            const float w = (k < HDIM) ? W2[k * CDIM + n] : 0.0f;
            v[b] = (short)f2bf(w);
        }
        *reinterpret_cast<bf16x8*>(w2p + (size_t)(fid * 64 + l) * 8) = v;
    } else {                              // b1p / cs1 reductions
        const int j = tid >> 2, p = tid & 3;
        float sb = 0.f, sg = 0.f;
        if (j < HDIM) {
            for (int c = p * 192; c < (p + 1) * 192; ++c) {
                const float w = W1[c * HDIM + j];
                sb += beta[c]  * w;
                sg += gamma[c] * w;
            }
        }
        sb += __shfl_xor(sb, 1); sb += __shfl_xor(sb, 2);
        sg += __shfl_xor(sg, 1); sg += __shfl_xor(sg, 2);
        if (p == 0 && j < HDIM) { b1p[j] = b1[j] + sb; cs1[j] = sg; }
    }
}

// ---------------- main fused kernel: 1 wave = 16 rows ----------------
// GEMM1 on RAW x (LN folded in afterwards):
//   hid = rstd*(x@W1' - mu*cs1) + b1'   then QuickGELU, then GEMM2 + residual.
// MFMA operand-swapped (A=weights, B=activations): lane's 4 acc regs = 4
// consecutive output channels of ONE row -> float4 epilogue.
// NO __syncthreads: the LDS hid tile is per-wave (same wave writes+reads it);
// same-wave ds ordering is guaranteed via compiler-inserted lgkmcnt waits.
__global__ __launch_bounds__(256) void mlp_kernel(
    const float* __restrict__ x,
    const float* __restrict__ b2,
    const unsigned short* __restrict__ w1p,
    const unsigned short* __restrict__ w2p,
    const float* __restrict__ b1p,
    const float* __restrict__ cs1,
    float* __restrict__ out)
{
    __shared__ __align__(16) unsigned short lds_hid[4][16][72]; // stride 72 -> 2-way banks (free)
    const int tid  = threadIdx.x;
    const int w    = tid >> 6;
    const int l    = tid & 63;
    const int lrow = l & 15;    // row of x within the 16-row tile
    const int lg   = l >> 4;    // k-group
    const size_t m0 = ((size_t)blockIdx.x * 4 + w) * 16;

    const float* __restrict__ xrow = x + (m0 + lrow) * CDIM + 8 * lg;
    const bf16x8* __restrict__ w1f = reinterpret_cast<const bf16x8*>(w1p);
    const bf16x8* __restrict__ w2f = reinterpret_cast<const bf16x8*>(w2p);

    f32x4 acc1[3];
    #pragma unroll
    for (int nt = 0; nt < 3; ++nt) { acc1[nt][0]=0.f; acc1[nt][1]=0.f; acc1[nt][2]=0.f; acc1[nt][3]=0.f; }

    // ---- GEMM1 + fused row stats, 2-deep x prefetch + 1-deep weight prefetch
    float rsum = 0.f, rsq = 0.f;
    f32x4 xc0 = *reinterpret_cast<const f32x4*>(xrow + 0);
    f32x4 xc1 = *reinterpret_cast<const f32x4*>(xrow + 4);
    f32x4 xn0 = *reinterpret_cast<const f32x4*>(xrow + 32);
    f32x4 xn1 = *reinterpret_cast<const f32x4*>(xrow + 36);
    bf16x8 wc0 = w1f[0 * 64 + l];
    bf16x8 wc1 = w1f[1 * 64 + l];
    bf16x8 wc2 = w1f[2 * 64 + l];
    #pragma unroll 2
    for (int kt = 0; kt < 24; ++kt) {
        const int kp = (kt + 2 <= 23) ? kt + 2 : 23;    // clamped (re-reads tail, no branch)
        f32x4 xp0 = *reinterpret_cast<const f32x4*>(xrow + kp * 32);
        f32x4 xp1 = *reinterpret_cast<const f32x4*>(xrow + kp * 32 + 4);
        const int kw = (kt + 1 <= 23) ? kt + 1 : 23;
        bf16x8 wn0 = w1f[(kw * 3 + 0) * 64 + l];
        bf16x8 wn1 = w1f[(kw * 3 + 1) * 64 + l];
        bf16x8 wn2 = w1f[(kw * 3 + 2) * 64 + l];

        bf16x8 bf;
        #pragma unroll
        for (int b = 0; b < 4; ++b) {
            rsum += xc0[b]; rsq += xc0[b] * xc0[b];
            rsum += xc1[b]; rsq += xc1[b] * xc1[b];
            bf[b]     = (short)f2bf(xc0[b]);
            bf[b + 4] = (short)f2bf(xc1[b]);
        }
        acc1[0] = __builtin_amdgcn_mfma_f32_16x16x32_bf16(wc0, bf, acc1[0], 0, 0, 0);
        acc1[1] = __builtin_amdgcn_mfma_f32_16x16x32_bf16(wc1, bf, acc1[1], 0, 0, 0);
        acc1[2] = __builtin_amdgcn_mfma_f32_16x16x32_bf16(wc2, bf, acc1[2], 0, 0, 0);

        xc0 = xn0; xc1 = xn1; xn0 = xp0; xn1 = xp1;
        wc0 = wn0; wc1 = wn1; wc2 = wn2;
    }
    rsum += __shfl_xor(rsum, 16); rsum += __shfl_xor(rsum, 32);
    rsq  += __shfl_xor(rsq , 16); rsq  += __shfl_xor(rsq , 32);
    const float mu   = rsum * (1.f / 768.f);
    const float var  = rsq * (1.f / 768.f) - mu * mu;
    const float rstd = rsqrtf(var + 1e-5f);

    // zero the k-pad region (cols 48..63) of this wave's hid tile
    *reinterpret_cast<unsigned long long*>(&lds_hid[w][l >> 2][48 + (l & 3) * 4]) = 0ull;

    // LN fixup + bias + QuickGELU -> LDS bf16 (lane owns 4 consecutive channels of row lrow)
    #pragma unroll
    for (int nt = 0; nt < 3; ++nt) {
        const int c4 = nt * 16 + 4 * lg;
        const f32x4 bb = *reinterpret_cast<const f32x4*>(b1p + c4);
        const f32x4 cs = *reinterpret_cast<const f32x4*>(cs1 + c4);
        u16x4 pk;
        #pragma unroll
        for (int r = 0; r < 4; ++r) {
            const float h = rstd * (acc1[nt][r] - mu * cs[r]) + bb[r];
            const float g = h / (1.f + __expf(-1.702f * h));
            pk[r] = f2bf(g);
        }
        *reinterpret_cast<u16x4*>(&lds_hid[w][lrow][c4]) = pk;
    }
    // wave-synchronous handoff (no __syncthreads): compiler orders via lgkmcnt

    const bf16x8 a2_0 = *reinterpret_cast<const bf16x8*>(&lds_hid[w][lrow][8 * lg]);
    const bf16x8 a2_1 = *reinterpret_cast<const bf16x8*>(&lds_hid[w][lrow][8 * lg + 32]);

    const float* __restrict__ xres = x   + (m0 + lrow) * CDIM;
    float* __restrict__       ores = out + (m0 + lrow) * CDIM;

    // ---- GEMM2 (48 ctiles in 6 chunks of 8) + fused residual epilogue.
    // Residual (longest-latency) loads issued FIRST in each chunk.
    #pragma unroll 1
    for (int ch = 0; ch < 6; ++ch) {
        f32x4 res[8];
        #pragma unroll
        for (int n8 = 0; n8 < 8; ++n8)
            res[n8] = *reinterpret_cast<const f32x4*>(xres + (ch * 8 + n8) * 16 + 4 * lg);
        f32x4 acc2[8];
        #pragma unroll
        for (int n8 = 0; n8 < 8; ++n8) { acc2[n8][0]=0.f; acc2[n8][1]=0.f; acc2[n8][2]=0.f; acc2[n8][3]=0.f; }
        #pragma unroll
        for (int n8 = 0; n8 < 8; ++n8) {
            const int ct = ch * 8 + n8;
            acc2[n8] = __builtin_amdgcn_mfma_f32_16x16x32_bf16(w2f[ct * 64 + l],        a2_0, acc2[n8], 0, 0, 0);
            acc2[n8] = __builtin_amdgcn_mfma_f32_16x16x32_bf16(w2f[(48 + ct) * 64 + l], a2_1, acc2[n8], 0, 0, 0);
        }
        #pragma unroll
        for (int n8 = 0; n8 < 8; ++n8) {
            const int c4 = (ch * 8 + n8) * 16 + 4 * lg;
            const f32x4 bb = *reinterpret_cast<const f32x4*>(b2 + c4);
            f32x4 o;
            #pragma unroll
            for (int r = 0; r < 4; ++r) o[r] = acc2[n8][r] + bb[r] + res[n8][r];
            *reinterpret_cast<f32x4*>(ores + c4) = o;
        }
    }
}

extern "C" void kernel_launch(void* const* d_in, const int* in_sizes, int n_in,
                              void* d_out, int out_size, void* d_ws, size_t ws_size,
                              hipStream_t stream)
{
    const float* x     = (const float*)d_in[0];
    const float* W1    = (const float*)d_in[1];
    const float* b1    = (const float*)d_in[2];
    const float* W2    = (const float*)d_in[3];
    const float* b2    = (const float*)d_in[4];
    const float* gamma = (const float*)d_in[5];
    const float* beta  = (const float*)d_in[6];
    float* out = (float*)d_out;

    unsigned short* w1p = (unsigned short*)d_ws;     // 72 frags * 512 B  = 73728 B
    unsigned short* w2p = w1p + 24 * 3 * 64 * 8;     // 96 frags * 512 B  = 98304 B
    float* b1p = (float*)(w2p + 2 * 48 * 64 * 8);    // 48 f32
    float* cs1 = b1p + 64;                           // 48 f32 (16B-aligned gap)

    const int M = in_sizes[0] / CDIM;   // 131072 rows
    const int tiles = M / 16;           // 8192 (one per wave)

    prep_kernel<<<dim3(43), dim3(256), 0, stream>>>(W1, b1, W2, gamma, beta, w1p, w2p, b1p, cs1);
    mlp_kernel<<<dim3(tiles / 4), dim3(256), 0, stream>>>(x, b2, w1p, w2p, b1p, cs1, out);
}